// Round 11
// baseline (71.277 us; speedup 1.0000x reference)
//
#include <hip/hip_runtime.h>
#include <hip/hip_bf16.h>

// Dynamic conv2d: B=16, C_in=64, H=W=128, C_out=64, K=5, ks=3, pad=1.
// R11: two independent barrier domains per CU. 256-thr (4-wave) blocks on
// 64-pix half-width, 8-row strips; bring = 4 x [8][66][8] bf16 = 33.8 KB
// -> 2 blocks/CU co-resident at the same 8-wave/CU budget. Reg-staged
// (R6-style) so the 66-pix slab needs no wave-uniform gll. A in registers.

typedef __attribute__((ext_vector_type(8))) __bf16 bf16x8;
typedef __attribute__((ext_vector_type(16))) float f32x16;
typedef __attribute__((ext_vector_type(4))) unsigned int u32x4;

#define NB 16
#define CI 64
#define CO 64
#define HH 128
#define WW 128
#define KBANK 5
#define ASTR 36864            // shorts of aggw per b: 2m * 36ks * 2g * 32co5 * 8j

__device__ __forceinline__ unsigned short f2bfu(float f) {
    __hip_bfloat16 h = __float2bfloat16(f);
    unsigned short s;
    __builtin_memcpy(&s, &h, 2);
    return s;
}

// ---------------- kernel 1: aggregate weights + bias ----------------
// aggw per b: [m(2)][ks(36)][g(2)][co5(32)][j(8)]; k = ks*16+g*8+j,
// tap = k>>6, ci = k&63, co = m*32+co5. Wave A-load = contiguous 1KB.
__global__ void prep_kernel(const float* __restrict__ weights,
                            const float* __restrict__ Wbank,
                            const float* __restrict__ bbank,
                            short* __restrict__ aggw,
                            float* __restrict__ aggb) {
    int idx = blockIdx.x * 256 + threadIdx.x;          // < 16*36864
    int b   = idx / ASTR;
    int rem = idx - b * ASTR;
    int j   = rem & 7;
    int co5 = (rem >> 3) & 31;
    int g   = (rem >> 8) & 1;
    int mk  = rem >> 9;
    int m   = mk / 36;
    int ks  = mk - m * 36;
    int co  = m * 32 + co5;
    int k   = ks * 16 + g * 8 + j;
    int tap = k >> 6;
    int ci  = k & 63;
    float s = 0.f;
#pragma unroll
    for (int kk = 0; kk < KBANK; ++kk)
        s += weights[b * KBANK + kk] * Wbank[((kk * CO + co) * CI + ci) * 9 + tap];
    aggw[idx] = (short)f2bfu(s);
    if (k == 0) {
        float sb = 0.f;
#pragma unroll
        for (int kk = 0; kk < KBANK; ++kk)
            sb += weights[b * KBANK + kk] * bbank[kk * CO + co];
        aggb[b * CO + co] = sb;
    }
}

// ---------------- kernel 2: streaming conv, half-width blocks ----------------
__device__ __forceinline__ void load16(const float* __restrict__ xb, int r,
                                       int w, int scg, float (&pv)[16]) {
#pragma unroll
    for (int i = 0; i < 16; ++i)
        pv[i] = xb[((size_t)(scg * 16 + i) * HH + r) * WW + w];
}

__device__ __forceinline__ void zero16(float (&pv)[16]) {
#pragma unroll
    for (int i = 0; i < 16; ++i) pv[i] = 0.f;
}

// bring slot: [ch 8][pixl 66][8 shorts]; pixl = w_in - P + 1 (0..65).
__device__ __forceinline__ void write16(short* __restrict__ slot, int sw, int scg,
                                        const float (&pv)[16]) {
#pragma unroll
    for (int h = 0; h < 2; ++h) {
        unsigned u0 = (unsigned)f2bfu(pv[h * 8 + 0]) | ((unsigned)f2bfu(pv[h * 8 + 1]) << 16);
        unsigned u1 = (unsigned)f2bfu(pv[h * 8 + 2]) | ((unsigned)f2bfu(pv[h * 8 + 3]) << 16);
        unsigned u2 = (unsigned)f2bfu(pv[h * 8 + 4]) | ((unsigned)f2bfu(pv[h * 8 + 5]) << 16);
        unsigned u3 = (unsigned)f2bfu(pv[h * 8 + 6]) | ((unsigned)f2bfu(pv[h * 8 + 7]) << 16);
        *(u32x4*)&slot[((scg * 2 + h) * 66 + sw + 1) * 8] = u32x4{u0, u1, u2, u3};
    }
}

__global__ __launch_bounds__(256, 2) void conv_kernel(const float* __restrict__ x,
                                                      const short* __restrict__ aggw,
                                                      const float* __restrict__ aggb,
                                                      float* __restrict__ out) {
    __shared__ short bring[4][8][66][8];               // 33,792 B -> 2 blocks/CU

    const int t   = threadIdx.x;                       // 0..255
    const int lin = blockIdx.x;                        // 0..511
    const int b   = (lin & 7) * 2 + ((lin >> 3) & 1);  // 2 b's per XCD slot
    const int sp  = lin >> 4;                          // 0..31
    const int strip = sp >> 1;                         // 0..15 (8-row strips)
    const int P   = (sp & 1) * 64;                     // pix half base
    const int r0  = strip * 8;

    const int l  = t & 63;
    const int wv = t >> 6;         // 0..3
    const int m  = wv >> 1;        // co half
    const int np = wv & 1;         // pix 32-range within the 64-pix half
    const int lm = l & 31;
    const int g  = l >> 5;

    const int sw  = t & 63;        // staging: local w
    const int scg = t >> 6;        // staging: 16-ci group

    // halo lane assignment (threads 0..127): side 0 = left (w=P-1, pixl 0),
    // side 1 = right (w=P+64, pixl 65)
    const int hside = t >> 6;                 // valid for t<128
    const int hci   = t & 63;
    const int hw    = P + (hside ? 64 : -1);
    const int hpixl = hside ? 65 : 0;
    const bool hvalid_w = ((unsigned)hw < 128u);

    const float* xb = x + (size_t)b * CI * HH * WW;
    const short* Ab = aggw + (size_t)b * ASTR + (size_t)m * 36 * 512;

    // A-half into registers (36 x bf16x8 = 144 VGPR), coalesced 1KB/wave
    bf16x8 A[36];
#pragma unroll
    for (int ks = 0; ks < 36; ++ks)
        A[ks] = *(const bf16x8*)(Ab + ks * 512 + l * 8);

    float bias[16];
#pragma unroll
    for (int rg = 0; rg < 16; ++rg)
        bias[rg] = aggb[b * CO + m * 32 + (rg & 3) + 8 * (rg >> 2) + 4 * g];

    // ---- prologue: stage rows r0-1, r0, r0+1 into slots 0,1,2 ----
#pragma unroll
    for (int pr = 0; pr < 3; ++pr) {
        const int r = r0 - 1 + pr;
        const bool rv = ((unsigned)r < 128u);
        float pv[16];
        float hval = 0.f;
        if (rv) load16(xb, r, P + sw, scg, pv); else zero16(pv);
        if (t < 128 && rv && hvalid_w)
            hval = xb[((size_t)hci * HH + r) * WW + hw];
        write16(&bring[pr][0][0][0], sw, scg, pv);
        if (t < 128)
            bring[pr][hci >> 3][hpixl][hci & 7] = (short)f2bfu(hval);
    }
    asm volatile("s_waitcnt lgkmcnt(0)" ::: "memory");
    __builtin_amdgcn_s_barrier();
    __builtin_amdgcn_sched_barrier(0);

    // ---- 8 row-steps ----
#pragma unroll
    for (int s = 0; s < 8; ++s) {
        const int r = r0 + s;

        // issue next-row loads at step start (consumed by write16 after MFMA)
        float pv[16];
        float hval = 0.f;
        const int rn = r + 2;
        const bool rv = (rn < 128);
        if (rv) load16(xb, rn, P + sw, scg, pv); else zero16(pv);
        if (t < 128 && rv && hvalid_w)
            hval = xb[((size_t)hci * HH + rn) * WW + hw];

        // MFMA: output row r from slots s, s+1, s+2 (mod 4)
        f32x16 acc = (f32x16)0.0f;
        __builtin_amdgcn_s_setprio(1);
#pragma unroll
        for (int ks = 0; ks < 36; ++ks) {
            const int tap = ks >> 2, q = ks & 3;
            const int dy = tap / 3, dx = tap - dy * 3;
            const short* sb = &bring[(s + dy) & 3][0][0][0];
            const int pixl = np * 32 + lm + dx;        // 0..65
            bf16x8 bv = *(const bf16x8*)&sb[((q * 2 + g) * 66 + pixl) * 8];
            acc = __builtin_amdgcn_mfma_f32_32x32x16_bf16(A[ks], bv, acc, 0, 0, 0);
        }
        __builtin_amdgcn_s_setprio(0);

        // output stores (fire-and-forget; retired by later steps' pv-waits)
        const int wc = P + np * 32 + lm;
#pragma unroll
        for (int rg = 0; rg < 16; ++rg) {
            int co = m * 32 + (rg & 3) + 8 * (rg >> 2) + 4 * g;
            out[(((size_t)b * CO + co) * HH + r) * WW + wc] = acc[rg] + bias[rg];
        }

        // stage row r+2 into slot (s+3)&3 (compiler waits pv's vmcnt only)
        write16(&bring[(s + 3) & 3][0][0][0], sw, scg, pv);
        if (t < 128)
            bring[(s + 3) & 3][hci >> 3][hpixl][hci & 7] = (short)f2bfu(hval);

        asm volatile("s_waitcnt lgkmcnt(0)" ::: "memory");
        __builtin_amdgcn_s_barrier();
        __builtin_amdgcn_sched_barrier(0);
    }
}

extern "C" void kernel_launch(void* const* d_in, const int* in_sizes, int n_in,
                              void* d_out, int out_size, void* d_ws, size_t ws_size,
                              hipStream_t stream) {
    const float* x       = (const float*)d_in[0];
    const float* weights = (const float*)d_in[1];
    const float* Wbank   = (const float*)d_in[2];
    const float* bbank   = (const float*)d_in[3];
    float* out = (float*)d_out;

    short* aggw = (short*)d_ws;                          // 1,179,648 B
    float* aggb = (float*)((char*)d_ws + 1179648);       //     4,096 B

    prep_kernel<<<dim3((NB * ASTR) / 256), dim3(256), 0, stream>>>(weights, Wbank, bbank, aggw, aggb);
    conv_kernel<<<dim3(512), dim3(256), 0, stream>>>(x, aggw, aggb, out);
}

// Round 12
// 40.053 us; speedup vs baseline: 1.7796x; 1.7796x over previous
//
#include <hip/hip_runtime.h>
#include <hip/hip_bf16.h>

// Dynamic conv2d: B=16, C_in=64, H=W=128, C_out=64, K=5, ks=3, pad=1.
// R12 = R10 (gll-staged fp32 ring -> LDS convert -> bf16 ring -> MFMA) with
// split-barrier publish: each step drains its OWN gll at the START of the
// next step (after a full step of latency cover), then a second s_barrier
// publishes. No new register liveness. Waste rows past strip bottom skipped.

typedef __attribute__((ext_vector_type(8))) __bf16 bf16x8;
typedef __attribute__((ext_vector_type(16))) float f32x16;
typedef __attribute__((ext_vector_type(4))) unsigned int u32x4;

#define NB 16
#define CI 64
#define CO 64
#define HH 128
#define WW 128
#define KBANK 5
#define ASTR 36864            // shorts of aggw per b: 2m * 36ks * 2g * 32co5 * 8j

__device__ __forceinline__ unsigned short f2bfu(float f) {
    __hip_bfloat16 h = __float2bfloat16(f);
    unsigned short s;
    __builtin_memcpy(&s, &h, 2);
    return s;
}

// ---------------- kernel 1: aggregate weights + bias ----------------
// aggw per b: [m(2)][ks(36)][g(2)][co5(32)][j(8)]; k = ks*16+g*8+j,
// tap = k>>6, ci = k&63, co = m*32+co5. Wave A-load = contiguous 1KB.
__global__ void prep_kernel(const float* __restrict__ weights,
                            const float* __restrict__ Wbank,
                            const float* __restrict__ bbank,
                            short* __restrict__ aggw,
                            float* __restrict__ aggb) {
    int idx = blockIdx.x * 256 + threadIdx.x;          // < 16*36864
    int b   = idx / ASTR;
    int rem = idx - b * ASTR;
    int j   = rem & 7;
    int co5 = (rem >> 3) & 31;
    int g   = (rem >> 8) & 1;
    int mk  = rem >> 9;
    int m   = mk / 36;
    int ks  = mk - m * 36;
    int co  = m * 32 + co5;
    int k   = ks * 16 + g * 8 + j;
    int tap = k >> 6;
    int ci  = k & 63;
    float s = 0.f;
#pragma unroll
    for (int kk = 0; kk < KBANK; ++kk)
        s += weights[b * KBANK + kk] * Wbank[((kk * CO + co) * CI + ci) * 9 + tap];
    aggw[idx] = (short)f2bfu(s);
    if (k == 0) {
        float sb = 0.f;
#pragma unroll
        for (int kk = 0; kk < KBANK; ++kk)
            sb += weights[b * KBANK + kk] * bbank[kk * CO + co];
        aggb[b * CO + co] = sb;
    }
}

// ---------------- kernel 2: streaming conv ----------------
#define WAITV(N) asm volatile("s_waitcnt vmcnt(" #N ")" ::: "memory")
#define WAITL0   asm volatile("s_waitcnt lgkmcnt(0)" ::: "memory")
#define SBAR     do { __builtin_amdgcn_s_barrier(); __builtin_amdgcn_sched_barrier(0); } while (0)

__global__ __launch_bounds__(512, 2) void conv_kernel(const float* __restrict__ x,
                                                      const short* __restrict__ aggw,
                                                      const float* __restrict__ aggb,
                                                      float* __restrict__ out) {
    __shared__ short bring[4][8][130][8];              // bf16 ring, 66,560 B
    __shared__ float fring[2][64][128];                // fp32 ring, 65,536 B

    const int t   = threadIdx.x;
    const int lin = blockIdx.x;                        // 256 blocks
    const int b   = (lin & 7) * 2 + ((lin >> 3) & 1);  // same-b blocks share an XCD
    const int r0  = (lin >> 4) * 8;                    // 8-row strip

    const int l  = t & 63;
    const int wv = t >> 6;         // 0..7
    const int m  = wv >> 2;        // co half
    const int nq = wv & 3;         // pix quarter
    const int lm = l & 31;
    const int g  = l >> 5;

    const float* xb = x + (size_t)b * CI * HH * WW;
    const short* Ab = aggw + (size_t)b * ASTR + (size_t)m * 36 * 512;

    // A-half into registers (36 x bf16x8), coalesced 1KB/wave loads
    bf16x8 A[36];
#pragma unroll
    for (int ks = 0; ks < 36; ++ks)
        A[ks] = *(const bf16x8*)(Ab + ks * 512 + l * 8);

    float bias[16];
#pragma unroll
    for (int rg = 0; rg < 16; ++rg)
        bias[rg] = aggb[b * CO + m * 32 + (rg & 3) + 8 * (rg >> 2) + 4 * g];

    // zero pix-halo (pix 0 and 129) of all 4 bf16 slots
    if (t < 64) {
        int slot = t >> 4, ch = (t >> 1) & 7, px = (t & 1) * 129;
        *(u32x4*)&bring[slot][ch][px][0] = u32x4{0u, 0u, 0u, 0u};
    }

    // stage: row r -> fp32 slot fs via global_load_lds (4 chunks/thread, 0 regs)
    auto stage = [&](int r, int fs) {
        float* fbase = &fring[fs][0][0];
#pragma unroll
        for (int i = 0; i < 4; ++i) {
            int c  = i * 512 + t;                      // chunk id, 16B each
            int ci = c >> 5;
            int w  = (c & 31) * 4;
            const float* src = xb + ((size_t)ci * HH + r) * WW + w;
            float* dst = fbase + (size_t)(i * 512 + (t & ~63)) * 4;  // wave-uniform base
            __builtin_amdgcn_global_load_lds(
                (const __attribute__((address_space(1))) void*)src,
                (__attribute__((address_space(3))) void*)dst, 16, 0, 0);
        }
    };

    // convert: fp32 slot -> bf16 ring slot bs (2 chunks/thread); zero => write 0s
    auto convertz = [&](const float* fbase, int bs, bool zero) {
#pragma unroll
        for (int k2 = 0; k2 < 2; ++k2) {
            int c   = k2 * 512 + t;
            int ch  = c >> 7;
            int pix = (c & 127) + 1;
            unsigned u0 = 0, u1 = 0, u2 = 0, u3 = 0;
            if (!zero) {
                const float* p = fbase + ch * 1024 + (pix - 1);
                u0 = (unsigned)f2bfu(p[0])   | ((unsigned)f2bfu(p[128]) << 16);
                u1 = (unsigned)f2bfu(p[256]) | ((unsigned)f2bfu(p[384]) << 16);
                u2 = (unsigned)f2bfu(p[512]) | ((unsigned)f2bfu(p[640]) << 16);
                u3 = (unsigned)f2bfu(p[768]) | ((unsigned)f2bfu(p[896]) << 16);
            }
            *(u32x4*)&bring[bs][ch][pix][0] = u32x4{u0, u1, u2, u3};
        }
    };

    // ---- prologue: bring rows r0-1,r0,r0+1 -> slots 0,1,2 ; gll(r0+2)->f0 left in flight
    if (r0 > 0) stage(r0 - 1, 1);                      // f1
    stage(r0, 0);                                      // f0
    WAITV(4); SBAR;                                    // r0-1 landed everywhere
    if (r0 > 0) convertz(&fring[1][0][0], 0, false);
    else        convertz(nullptr,         0, true);
    WAITV(0);                                          // r0 landed (own)
    WAITL0; SBAR;                                      // publish bring0 + r0 landing
    convertz(&fring[0][0][0], 1, false);               // r0 -> bring1
    stage(r0 + 1, 1);                                  // f1 (its reads drained above)
    WAITL0; SBAR;                                      // publish bring1
    WAITV(0); SBAR;                                    // r0+1 landed everywhere
    convertz(&fring[1][0][0], 2, false);               // r0+1 -> bring2
    stage(r0 + 2, 0);                                  // f0 (reads drained 2 barriers ago)
    WAITL0; SBAR;                                      // publish bring2; gll(r0+2) in flight

    // ---- 8 row-steps, split-barrier publish ----
#pragma unroll
    for (int s = 0; s < 8; ++s) {
        const int r = r0 + s;

        // drain own gll issued LAST step (full step of cover), then publish
        if (s == 0) { WAITV(0); } else { WAITV(16); }
        SBAR;

        // convert row r+2 (fring slot s&1) -> bring slot (s+3)&3 ; only if used
        if (s <= 6) {
            if (r + 2 <= 127) convertz(&fring[s & 1][0][0], (s + 3) & 3, false);
            else              convertz(nullptr,             (s + 3) & 3, true);
        }

        // issue next row's gll (drained at start of next step)
        if (s <= 5 && r + 3 <= 127) stage(r + 3, (s + 1) & 1);

        // MFMA: output row r from bf16 slots (s, s+1, s+2)
        f32x16 acc = (f32x16)0.0f;
#pragma unroll
        for (int ks = 0; ks < 36; ++ks) {
            const int tap = ks >> 2, q = ks & 3;
            const int dy = tap / 3, dx = tap - dy * 3;
            const short* sb = &bring[(s + dy) & 3][0][0][0];
            const int pix = nq * 32 + dx + lm;
            bf16x8 bv = *(const bf16x8*)&sb[((q * 2 + g) * 130 + pix) * 8];
            acc = __builtin_amdgcn_mfma_f32_32x32x16_bf16(A[ks], bv, acc, 0, 0, 0);
        }

        // output stores (fire-and-forget; retired by NEXT step's WAITV(16))
        const int wc = nq * 32 + lm;
#pragma unroll
        for (int rg = 0; rg < 16; ++rg) {
            int co = m * 32 + (rg & 3) + 8 * (rg >> 2) + 4 * g;
            out[(((size_t)b * CO + co) * HH + r) * WW + wc] = acc[rg] + bias[rg];
        }

        // end-of-step: drain LDS ops only (stores + gll stay in flight)
        WAITL0;
        SBAR;
    }
}

extern "C" void kernel_launch(void* const* d_in, const int* in_sizes, int n_in,
                              void* d_out, int out_size, void* d_ws, size_t ws_size,
                              hipStream_t stream) {
    const float* x       = (const float*)d_in[0];
    const float* weights = (const float*)d_in[1];
    const float* Wbank   = (const float*)d_in[2];
    const float* bbank   = (const float*)d_in[3];
    float* out = (float*)d_out;

    short* aggw = (short*)d_ws;                          // 1,179,648 B
    float* aggb = (float*)((char*)d_ws + 1179648);       //     4,096 B

    prep_kernel<<<dim3((NB * ASTR) / 256), dim3(256), 0, stream>>>(weights, Wbank, bbank, aggw, aggb);
    conv_kernel<<<dim3(256), dim3(512), 0, stream>>>(x, aggw, aggb, out);
}